// Round 10
// baseline (2050.650 us; speedup 1.0000x reference)
//
#include <hip/hip_runtime.h>
#include <hip/hip_cooperative_groups.h>
#include <math.h>

namespace cg = cooperative_groups;

// Problem dims
constexpr int B_  = 4;
constexpr int T_  = 16;
constexpr int CIN = 32;
constexpr int HID = 64;
constexpr int HH  = 64;
constexpr int WW  = 64;
constexpr int HW  = HH * WW; // 4096

// ---------------- MFMA path config ----------------
constexpr int TR = 8,  TC = 16;         // output pixel tile: 8 rows x 16 cols
constexpr int PR = TR + 2, PC = TC + 2; // 10 x 18 (halo)
constexpr int CSL = 40;                 // channel slots per pixel (80B)
constexpr int KCH = 32;                 // channels per K-chunk
// A slab (per chunk, per hg): [gate3][tap9*4+klgrp][row16] 16B granules
constexpr int ASLAB_HW  = 3 * 36 * 16 * 8;            // 13824 halfwords (27648 B)
constexpr int ATOTAL    = 12 * ASLAB_HW;              // 165888 weight elements
constexpr int TIN_HW    = PR * PC * CSL;              // 7200 halfwords (14400 B)
constexpr int TIN_GRAN  = TIN_HW / 8;                 // 900 granules
constexpr int ROW_HW    = 66 * CSL;                   // 2640 hw per padded image row
constexpr int PIMG_HW   = 66 * ROW_HW;                // 174240 hw per padded image

// ws layout (halfword offsets)
constexpr size_t A2_HW    = (size_t)ATOTAL;
constexpr size_t XT_OFF   = A2_HW;
constexpr size_t XT_HW    = (size_t)64 * PIMG_HW;
constexpr size_t HT_OFF   = XT_OFF + XT_HW;
constexpr size_t HTBUF_HW = (size_t)8 * PIMG_HW;      // [b4][chunk2] images
constexpr size_t WS_NEED_BYTES = (A2_HW + XT_HW + 2 * HTBUF_HW) * 2;

typedef __attribute__((ext_vector_type(8))) short bf16x8;
typedef __attribute__((ext_vector_type(4))) float f32x4;

#define GLOAD_LDS16(gsrc, ldst) \
  __builtin_amdgcn_global_load_lds((const __attribute__((address_space(1))) void*)(gsrc), \
                                   (__attribute__((address_space(3))) void*)(ldst), 16, 0, 0)

__device__ inline unsigned short f2bf(float f) {
    union { float f; unsigned u; } v; v.f = f;
    return (unsigned short)((v.u + 0x7FFFu + ((v.u >> 16) & 1u)) >> 16);
}
__device__ inline float bf2f(unsigned short h) {
    union { unsigned u; float f; } v; v.u = (unsigned)h << 16; return v.f;
}

// ---- prepass 1: weights -> bf16, transposed granules [ch][hg][gate][tap*4+klgrp][row16] ----
__global__ void wconv(const float* __restrict__ Wi, const float* __restrict__ Wh,
                      unsigned short* __restrict__ A2) {
    int idx = blockIdx.x * 256 + threadIdx.x;
    if (idx >= ATOTAL) return;
    int ic  = idx & 31;
    int r1  = idx >> 5;
    int tap = r1 % 9;
    int r2  = r1 / 9;
    int m   = r2 & 15;
    int r3  = r2 >> 4;
    int gt  = r3 % 3;
    int r4  = r3 / 3;
    int hg  = r4 & 3;
    int ch  = r4 >> 2;
    int o   = gt * 64 + hg * 16 + m;
    float w = (ch == 0) ? Wi[(o * CIN + ic) * 9 + tap]
                        : Wh[(o * HID + (ch - 1) * 32 + ic) * 9 + tap];
    size_t dst = (size_t)(ch * 4 + hg) * ASLAB_HW
               + ((size_t)(gt * 36 + tap * 4 + (ic >> 3)) * 16 + m) * 8 + (ic & 7);
    A2[dst] = f2bf(w);
}

// ---- prepass 2: x -> channel-last padded bf16 xT[bt][66][66][40] (coalesced) ----
__global__ void xfill(const float* __restrict__ x, unsigned short* __restrict__ xT) {
    const int riT = blockIdx.x;   // 0..65
    const int bt  = blockIdx.y;   // 0..63
    unsigned short* dst = xT + (size_t)bt * PIMG_HW + (size_t)riT * ROW_HW;
    __shared__ float lds[64 * 41];

    const bool interior = (riT >= 1 && riT <= 64);
    if (interior) {
        const float* src = x + (size_t)bt * 32 * HW + (riT - 1) * WW;
        const int p = threadIdx.x & 63;
        #pragma unroll
        for (int j = 0; j < 8; ++j) {
            int c = j * 4 + (threadIdx.x >> 6);
            lds[p * 41 + c] = src[c * HW + p];   // coalesced 256B reads
        }
    }
    __syncthreads();
    for (int g = threadIdx.x; g < ROW_HW / 8; g += 256) {   // 330 granules
        bf16x8 vv;
        #pragma unroll
        for (int k = 0; k < 8; ++k) {
            int off = g * 8 + k;
            int px = off / CSL, slot = off - px * CSL;
            float v = 0.f;
            if (interior && slot < 32 && px >= 1 && px <= 64)
                v = lds[(px - 1) * 41 + slot];
            vv[k] = (short)f2bf(v);
        }
        *(bf16x8*)(dst + g * 8) = vv;                        // coalesced 16B writes
    }
}

// ---- prepass 3: zero both hT buffers (halo ring must be 0) ----
__global__ void hzero(unsigned short* __restrict__ hT, int n16) {
    int i = blockIdx.x * 256 + threadIdx.x;
    if (i < n16) ((f32x4*)hT)[i] = f32x4{0.f, 0.f, 0.f, 0.f};
}

// ================= fused all-timesteps cooperative kernel =================
// grid (32 tiles, 4 hg, 4 b) = 512 blocks = 2/CU; 256 thr.
__global__ __launch_bounds__(256, 2) void convgru_all(
    const unsigned short* __restrict__ xT,   // [64][66][66][40]
    const unsigned short* __restrict__ A2,   // transposed slabs
    unsigned short* __restrict__ hT0,        // [b][chunk][66][66][40]
    unsigned short* __restrict__ hT1,
    float* __restrict__ out)
{
    cg::grid_group gg = cg::this_grid();

    __shared__ __align__(16) unsigned short tXa[TIN_HW];  // x tile (even t)
    __shared__ __align__(16) unsigned short tXb[TIN_HW];  // x tile (odd t)
    __shared__ __align__(16) unsigned short tL[TIN_HW];   // h ch 0-31
    __shared__ __align__(16) unsigned short tH[TIN_HW];   // h ch 32-63

    const int tid  = threadIdx.x;
    const int lane = tid & 63, wave = tid >> 6;
    const int px   = lane & 15, kl = lane >> 4;  // px = A row = B col = C col
    const int ty = blockIdx.x >> 2, tx = blockIdx.x & 3;
    const int hg = blockIdx.y, b = blockIdx.z;
    const int gy0 = ty * TR, gx0 = tx * TC;
    const int rowbase = gy0 * 66 + gx0;

    f32x4 accR[2], accZ[2], accNX[2], accNH[2];
    bf16x8 a[27];

    auto stage_tin = [&](const unsigned short* src, unsigned short* dst) {
        #pragma unroll
        for (int j = 0; j < 4; ++j) {
            int G = tid + j * 256;
            if (G < TIN_GRAN) {
                int r = G / 90, w = G - 90 * r;   // 90 granules per halo row
                GLOAD_LDS16(src + (size_t)(rowbase + r * 66) * CSL + w * 8, dst + G * 8);
            }
        }
    };
    auto regA = [&](int ch) {
        const unsigned short* s = A2 + (size_t)(ch * 4 + hg) * ASLAB_HW + lane * 8;
        #pragma unroll
        for (int i = 0; i < 27; ++i)
            a[i] = *(const bf16x8*)(s + (size_t)((i / 9) * 36 + (i % 9) * 4) * 128);
    };

    const int rb = (wave * 2 * PC + px) * CSL + kl * 8;

    auto compute = [&](const unsigned short* tb, bool isX) {
        bf16x8 P[4][3];   // rows 2w..2w+3 x col shifts 0..2 (12 dedup'd reads)
        #pragma unroll
        for (int r = 0; r < 4; ++r)
            #pragma unroll
            for (int s = 0; s < 3; ++s)
                P[r][s] = *(const bf16x8*)(tb + rb + (r * PC + s) * CSL);
        #pragma unroll
        for (int dy = 0; dy < 3; ++dy) {
            #pragma unroll
            for (int dx = 0; dx < 3; ++dx) {
                const int tap = dy * 3 + dx;
                bf16x8 b0 = P[dy][dx], b1 = P[dy + 1][dx];
                bf16x8 ar = a[tap], az = a[9 + tap], an = a[18 + tap];
                accR[0] = __builtin_amdgcn_mfma_f32_16x16x32_bf16(ar, b0, accR[0], 0, 0, 0);
                accR[1] = __builtin_amdgcn_mfma_f32_16x16x32_bf16(ar, b1, accR[1], 0, 0, 0);
                accZ[0] = __builtin_amdgcn_mfma_f32_16x16x32_bf16(az, b0, accZ[0], 0, 0, 0);
                accZ[1] = __builtin_amdgcn_mfma_f32_16x16x32_bf16(az, b1, accZ[1], 0, 0, 0);
                if (isX) {
                    accNX[0] = __builtin_amdgcn_mfma_f32_16x16x32_bf16(an, b0, accNX[0], 0, 0, 0);
                    accNX[1] = __builtin_amdgcn_mfma_f32_16x16x32_bf16(an, b1, accNX[1], 0, 0, 0);
                } else {
                    accNH[0] = __builtin_amdgcn_mfma_f32_16x16x32_bf16(an, b0, accNH[0], 0, 0, 0);
                    accNH[1] = __builtin_amdgcn_mfma_f32_16x16x32_bf16(an, b1, accNH[1], 0, 0, 0);
                }
            }
        }
    };

    // prime: x tile for t=0
    stage_tin(xT + (size_t)(b * T_) * PIMG_HW, tXa);

    for (int t = 0; t < T_; ++t) {
        const unsigned short* hTrd = (t & 1) ? hT1 : hT0;
        unsigned short*       hTwr = (t & 1) ? hT0 : hT1;
        const unsigned short* txc  = (t & 1) ? tXb : tXa;
        unsigned short*       txn  = (t & 1) ? tXa : tXb;

        if (t > 0) {
            stage_tin(hTrd + (size_t)(b * 2 + 0) * PIMG_HW, tL);
            stage_tin(hTrd + (size_t)(b * 2 + 1) * PIMG_HW, tH);
        }
        regA(0);
        __syncthreads();                 // drains vmcnt: x + h tiles ready

        #pragma unroll
        for (int i = 0; i < 2; ++i) {
            accR[i] = f32x4{0.f,0.f,0.f,0.f}; accZ[i] = f32x4{0.f,0.f,0.f,0.f};
            accNX[i] = f32x4{0.f,0.f,0.f,0.f}; accNH[i] = f32x4{0.f,0.f,0.f,0.f};
        }

        compute(txc, true);
        if (t + 1 < T_)                  // prefetch next x under h-compute
            stage_tin(xT + (size_t)(b * T_ + t + 1) * PIMG_HW, txn);
        if (t > 0) {
            regA(1); compute(tL, false);
            regA(2); compute(tH, false);
        }

        // ---- epilogue: gates + state update; h_prev (bf16) from retained LDS ----
        float* outp = out + ((size_t)(b * T_ + t)) * HID * HW;
        const int c0   = hg * 16 + kl * 4;
        const int slot = c0 & 31;
        const unsigned short* hbuf = (hg < 2) ? tL : tH;
        #pragma unroll
        for (int g = 0; g < 2; ++g) {
            int gy = gy0 + wave * 2 + g;
            int gx = gx0 + px;
            float hvf[4] = {0.f, 0.f, 0.f, 0.f};
            if (t > 0) {
                const unsigned short* hp =
                    hbuf + ((wave * 2 + g + 1) * PC + (px + 1)) * CSL + slot;
                #pragma unroll
                for (int q = 0; q < 4; ++q) hvf[q] = bf2f(hp[q]);
            }
            unsigned short hvals[4];
            #pragma unroll
            for (int q = 0; q < 4; ++q) {
                int c = c0 + q;
                float sr = __builtin_amdgcn_rcpf(1.f + __expf(-accR[g][q]));
                float sz = __builtin_amdgcn_rcpf(1.f + __expf(-accZ[g][q]));
                float ag = accNX[g][q] + sr * accNH[g][q];
                float nn = 2.f * __builtin_amdgcn_rcpf(1.f + __expf(-2.f * ag)) - 1.f;
                float hn = nn + sz * (hvf[q] - nn);
                outp[(size_t)c * HW + gy * WW + gx] = hn;
                hvals[q] = f2bf(hn);
            }
            unsigned short* hd = hTwr + (size_t)(b * 2 + (c0 >> 5)) * PIMG_HW
                               + (size_t)((gy + 1) * 66 + (gx + 1)) * CSL + slot;
            *(uint2*)hd = *(const uint2*)hvals;
        }

        __threadfence();                 // release h/out writes device-wide
        gg.sync();                       // all blocks: step t complete
    }
}

// ================= r9 per-step kernel (fallback if cooperative launch fails) =================
__global__ __launch_bounds__(256, 2) void convgru_step9(
    const unsigned short* __restrict__ xT,
    const unsigned short* __restrict__ A2,
    const unsigned short* __restrict__ hTrd,
    unsigned short* __restrict__ hTwr,
    float* __restrict__ out, int t)
{
    __shared__ __align__(16) unsigned short t0s[TIN_HW];
    __shared__ __align__(16) unsigned short t1s[TIN_HW];
    __shared__ __align__(16) unsigned short t2s[TIN_HW];

    const int tid  = threadIdx.x;
    const int lane = tid & 63, wave = tid >> 6;
    const int px   = lane & 15, kl = lane >> 4;
    const int ty = blockIdx.x >> 2, tx = blockIdx.x & 3;
    const int hg = blockIdx.y, b = blockIdx.z;
    const int gy0 = ty * TR, gx0 = tx * TC;

    const unsigned short* xs = xT + (size_t)(b * T_ + t) * PIMG_HW;
    const int rowbase = gy0 * 66 + gx0;

    f32x4 accR[2] = {}, accZ[2] = {}, accNX[2] = {}, accNH[2] = {};
    bf16x8 a[27];

    auto stage_tin = [&](const unsigned short* src, unsigned short* dst) {
        #pragma unroll
        for (int j = 0; j < 4; ++j) {
            int G = tid + j * 256;
            if (G < TIN_GRAN) {
                int r = G / 90, w = G - 90 * r;
                GLOAD_LDS16(src + (size_t)(rowbase + r * 66) * CSL + w * 8, dst + G * 8);
            }
        }
    };
    auto regA = [&](int ch) {
        const unsigned short* s = A2 + (size_t)(ch * 4 + hg) * ASLAB_HW + lane * 8;
        #pragma unroll
        for (int i = 0; i < 27; ++i)
            a[i] = *(const bf16x8*)(s + (size_t)((i / 9) * 36 + (i % 9) * 4) * 128);
    };

    const int rb = (wave * 2 * PC + px) * CSL + kl * 8;

    auto compute = [&](const unsigned short* tb, bool isX) {
        bf16x8 P[4][3];
        #pragma unroll
        for (int r = 0; r < 4; ++r)
            #pragma unroll
            for (int s = 0; s < 3; ++s)
                P[r][s] = *(const bf16x8*)(tb + rb + (r * PC + s) * CSL);
        #pragma unroll
        for (int dy = 0; dy < 3; ++dy) {
            #pragma unroll
            for (int dx = 0; dx < 3; ++dx) {
                const int tap = dy * 3 + dx;
                bf16x8 b0 = P[dy][dx], b1 = P[dy + 1][dx];
                bf16x8 ar = a[tap], az = a[9 + tap], an = a[18 + tap];
                accR[0] = __builtin_amdgcn_mfma_f32_16x16x32_bf16(ar, b0, accR[0], 0, 0, 0);
                accR[1] = __builtin_amdgcn_mfma_f32_16x16x32_bf16(ar, b1, accR[1], 0, 0, 0);
                accZ[0] = __builtin_amdgcn_mfma_f32_16x16x32_bf16(az, b0, accZ[0], 0, 0, 0);
                accZ[1] = __builtin_amdgcn_mfma_f32_16x16x32_bf16(az, b1, accZ[1], 0, 0, 0);
                if (isX) {
                    accNX[0] = __builtin_amdgcn_mfma_f32_16x16x32_bf16(an, b0, accNX[0], 0, 0, 0);
                    accNX[1] = __builtin_amdgcn_mfma_f32_16x16x32_bf16(an, b1, accNX[1], 0, 0, 0);
                } else {
                    accNH[0] = __builtin_amdgcn_mfma_f32_16x16x32_bf16(an, b0, accNH[0], 0, 0, 0);
                    accNH[1] = __builtin_amdgcn_mfma_f32_16x16x32_bf16(an, b1, accNH[1], 0, 0, 0);
                }
            }
        }
    };

    stage_tin(xs, t0s);
    if (t > 0) {
        stage_tin(hTrd + (size_t)(b * 2 + 0) * PIMG_HW, t1s);
        stage_tin(hTrd + (size_t)(b * 2 + 1) * PIMG_HW, t2s);
    }
    regA(0);
    __syncthreads();
    compute(t0s, true);
    if (t > 0) {
        regA(1); compute(t1s, false);
        regA(2); compute(t2s, false);
    }

    float* outp = out + ((size_t)(b * T_ + t)) * HID * HW;
    const int c0   = hg * 16 + kl * 4;
    const int slot = c0 & 31;
    const unsigned short* hbuf = (hg < 2) ? t1s : t2s;
    #pragma unroll
    for (int g = 0; g < 2; ++g) {
        int gy = gy0 + wave * 2 + g;
        int gx = gx0 + px;
        float hvf[4] = {0.f, 0.f, 0.f, 0.f};
        if (t > 0) {
            const unsigned short* hp =
                hbuf + ((wave * 2 + g + 1) * PC + (px + 1)) * CSL + slot;
            #pragma unroll
            for (int q = 0; q < 4; ++q) hvf[q] = bf2f(hp[q]);
        }
        unsigned short hvals[4];
        #pragma unroll
        for (int q = 0; q < 4; ++q) {
            int c = c0 + q;
            float sr = __builtin_amdgcn_rcpf(1.f + __expf(-accR[g][q]));
            float sz = __builtin_amdgcn_rcpf(1.f + __expf(-accZ[g][q]));
            float ag = accNX[g][q] + sr * accNH[g][q];
            float nn = 2.f * __builtin_amdgcn_rcpf(1.f + __expf(-2.f * ag)) - 1.f;
            float hn = nn + sz * (hvf[q] - nn);
            outp[(size_t)c * HW + gy * WW + gx] = hn;
            hvals[q] = f2bf(hn);
        }
        unsigned short* hd = hTwr + (size_t)(b * 2 + (c0 >> 5)) * PIMG_HW
                           + (size_t)((gy + 1) * 66 + (gx + 1)) * CSL + slot;
        *(uint2*)hd = *(const uint2*)hvals;
    }
}

extern "C" void kernel_launch(void* const* d_in, const int* in_sizes, int n_in,
                              void* d_out, int out_size, void* d_ws, size_t ws_size,
                              hipStream_t stream) {
    const float* x  = (const float*)d_in[0];
    const float* Wi = (const float*)d_in[1];
    const float* Wh = (const float*)d_in[2];
    float* out = (float*)d_out;

    unsigned short* A2  = (unsigned short*)d_ws;
    unsigned short* xT  = A2 + XT_OFF;
    unsigned short* hT0 = A2 + HT_OFF;
    unsigned short* hT1 = hT0 + HTBUF_HW;

    wconv<<<(ATOTAL + 255) / 256, 256, 0, stream>>>(Wi, Wh, A2);
    xfill<<<dim3(66, 64), 256, 0, stream>>>(x, xT);
    {
        int n16 = (int)(2 * HTBUF_HW / 8);
        hzero<<<(n16 + 255) / 256, 256, 0, stream>>>(hT0, n16);
    }

    const unsigned short* xTc = xT;
    const unsigned short* A2c = A2;
    void* args[] = { (void*)&xTc, (void*)&A2c, (void*)&hT0, (void*)&hT1, (void*)&out };
    hipError_t e = hipLaunchCooperativeKernel((void*)convgru_all, dim3(32, 4, 4),
                                              dim3(256, 1, 1), args, 0, stream);
    if (e != hipSuccess) {
        // fallback: identical math, one launch per step
        for (int t = 0; t < T_; ++t) {
            unsigned short* rd = (t & 1) ? hT1 : hT0;
            unsigned short* wr = (t & 1) ? hT0 : hT1;
            convgru_step9<<<dim3(32, 4, 4), 256, 0, stream>>>(xT, A2, rd, wr, out, t);
        }
    }
}

// Round 11
// 166.708 us; speedup vs baseline: 12.3008x; 12.3008x over previous
//
#include <hip/hip_runtime.h>
#include <math.h>

// Problem dims
constexpr int B_  = 4;
constexpr int T_  = 16;
constexpr int CIN = 32;
constexpr int HID = 64;
constexpr int HH  = 64;
constexpr int WW  = 64;
constexpr int HW  = HH * WW; // 4096

// ---------------- MFMA path config ----------------
constexpr int TR = 8,  TC = 16;         // output pixel tile: 8 rows x 16 cols
constexpr int PR = TR + 2, PC = TC + 2; // 10 x 18 (halo)
constexpr int CSL = 40;                 // channel slots per pixel (80B)
constexpr int KCH = 32;                 // channels per K-chunk
// A slab (per chunk, per hg): [gate3][tap9*4+klgrp][row16] 16B granules
constexpr int ASLAB_HW  = 3 * 36 * 16 * 8;            // 13824 halfwords (27648 B)
constexpr int ATOTAL    = 12 * ASLAB_HW;              // 165888 weight elements
constexpr int TIN_HW    = PR * PC * CSL;              // 7200 halfwords (14400 B)
constexpr int TIN_GRAN  = TIN_HW / 8;                 // 900 granules
constexpr int ROW_HW    = 66 * CSL;                   // 2640 hw per padded image row
constexpr int PIMG_HW   = 66 * ROW_HW;                // 174240 hw per padded image

// ws layout (halfword offsets)
constexpr size_t A2_HW    = (size_t)ATOTAL;
constexpr size_t XT_OFF   = A2_HW;
constexpr size_t XT_HW    = (size_t)64 * PIMG_HW;
constexpr size_t HT_OFF   = XT_OFF + XT_HW;
constexpr size_t HTBUF_HW = (size_t)8 * PIMG_HW;      // [b4][chunk2] images
constexpr size_t WS_NEED_BYTES = (A2_HW + XT_HW + 2 * HTBUF_HW) * 2;

// fused prepass block ranges
constexpr int PB_XFILL = 66 * 64;                      // 4224
constexpr int PB_WCONV = (ATOTAL + 255) / 256;         // 648
constexpr int HZ_GRAN  = (int)(2 * HTBUF_HW / 8);      // 348480 16B granules
constexpr int PB_HZERO = (HZ_GRAN + 255) / 256;        // 1362
constexpr int PB_TOTAL = PB_XFILL + PB_WCONV + PB_HZERO;

typedef __attribute__((ext_vector_type(8))) short bf16x8;
typedef __attribute__((ext_vector_type(4))) float f32x4;

#define GLOAD_LDS16(gsrc, ldst) \
  __builtin_amdgcn_global_load_lds((const __attribute__((address_space(1))) void*)(gsrc), \
                                   (__attribute__((address_space(3))) void*)(ldst), 16, 0, 0)

__device__ inline unsigned short f2bf(float f) {
    union { float f; unsigned u; } v; v.f = f;
    return (unsigned short)((v.u + 0x7FFFu + ((v.u >> 16) & 1u)) >> 16);
}
__device__ inline float bf2f(unsigned short h) {
    union { unsigned u; float f; } v; v.u = (unsigned)h << 16; return v.f;
}

// ---- fused prepass: xfill | wconv | hzero (branch on block range) ----
__global__ void prep(const float* __restrict__ x,
                     const float* __restrict__ Wi, const float* __restrict__ Wh,
                     unsigned short* __restrict__ A2,
                     unsigned short* __restrict__ xT,
                     unsigned short* __restrict__ hT) {
    __shared__ float lds[64 * 41];
    const int bid = blockIdx.x;

    if (bid < PB_XFILL) {
        // ---- xfill: x -> channel-last padded bf16 xT[bt][66][66][40] ----
        const int riT = bid % 66;
        const int bt  = bid / 66;
        unsigned short* dst = xT + (size_t)bt * PIMG_HW + (size_t)riT * ROW_HW;
        const bool interior = (riT >= 1 && riT <= 64);
        if (interior) {
            const float* src = x + (size_t)bt * 32 * HW + (riT - 1) * WW;
            const int p = threadIdx.x & 63;
            #pragma unroll
            for (int j = 0; j < 8; ++j) {
                int c = j * 4 + (threadIdx.x >> 6);
                lds[p * 41 + c] = src[c * HW + p];     // coalesced 256B reads
            }
        }
        __syncthreads();
        for (int g = threadIdx.x; g < ROW_HW / 8; g += 256) {
            bf16x8 vv;
            #pragma unroll
            for (int k = 0; k < 8; ++k) {
                int off = g * 8 + k;
                int px = off / CSL, slot = off - px * CSL;
                float v = 0.f;
                if (interior && slot < 32 && px >= 1 && px <= 64)
                    v = lds[(px - 1) * 41 + slot];
                vv[k] = (short)f2bf(v);
            }
            *(bf16x8*)(dst + g * 8) = vv;              // coalesced 16B writes
        }
    } else if (bid < PB_XFILL + PB_WCONV) {
        // ---- wconv: weights -> bf16 transposed granules [ch][hg][gate][tap*4+klgrp][row16] ----
        int idx = (bid - PB_XFILL) * 256 + threadIdx.x;
        if (idx >= ATOTAL) return;
        int ic  = idx & 31;
        int r1  = idx >> 5;
        int tap = r1 % 9;
        int r2  = r1 / 9;
        int m   = r2 & 15;
        int r3  = r2 >> 4;
        int gt  = r3 % 3;
        int r4  = r3 / 3;
        int hg  = r4 & 3;
        int ch  = r4 >> 2;
        int o   = gt * 64 + hg * 16 + m;
        float w = (ch == 0) ? Wi[(o * CIN + ic) * 9 + tap]
                            : Wh[(o * HID + (ch - 1) * 32 + ic) * 9 + tap];
        size_t dst = (size_t)(ch * 4 + hg) * ASLAB_HW
                   + ((size_t)(gt * 36 + tap * 4 + (ic >> 3)) * 16 + m) * 8 + (ic & 7);
        A2[dst] = f2bf(w);
    } else {
        // ---- hzero: zero both hT buffers (halo ring must be 0) ----
        int i = (bid - PB_XFILL - PB_WCONV) * 256 + threadIdx.x;
        if (i < HZ_GRAN) ((f32x4*)hT)[i] = f32x4{0.f, 0.f, 0.f, 0.f};
    }
}

// ---- fused ConvGRU step: A in VGPRs (pipelined reload), dedup B-reads, 1 barrier ----
// grid (32 tiles, 4 hg, 4 b), 256 thr (4 waves; wave w owns output rows 2w,2w+1)
__global__ __launch_bounds__(256, 2) void convgru_mfma(
    const unsigned short* __restrict__ xT,   // [64][66][66][40]
    const unsigned short* __restrict__ A2,   // transposed slabs
    const unsigned short* __restrict__ hTrd, // [b][chunk][66][66][40] (t-1)
    unsigned short* __restrict__ hTwr,       // same layout (t)
    float* __restrict__ out, int t)
{
    __shared__ __align__(16) unsigned short t0s[TIN_HW];  // x tile
    __shared__ __align__(16) unsigned short t1s[TIN_HW];  // h ch 0-31
    __shared__ __align__(16) unsigned short t2s[TIN_HW];  // h ch 32-63

    const int tid  = threadIdx.x;
    const int lane = tid & 63, wave = tid >> 6;
    const int px   = lane & 15, kl = lane >> 4;  // px = A row = B col = C col
    const int ty = blockIdx.x >> 2, tx = blockIdx.x & 3;
    const int hg = blockIdx.y, b = blockIdx.z;
    const int gy0 = ty * TR, gx0 = tx * TC;

    const unsigned short* xs = xT + (size_t)(b * T_ + t) * PIMG_HW;
    const int rowbase = gy0 * 66 + gx0;   // halo-origin pixel index in padded image

    f32x4 accR[2] = {}, accZ[2] = {}, accNX[2] = {}, accNH[2] = {};
    bf16x8 a[27];                         // current chunk's A fragments (statically indexed)

    auto stage_tin = [&](const unsigned short* src, unsigned short* dst) {
        #pragma unroll
        for (int j = 0; j < 4; ++j) {
            int G = tid + j * 256;
            if (G < TIN_GRAN) {
                int r = G / 90, w = G - 90 * r;   // 90 granules per halo row
                GLOAD_LDS16(src + (size_t)(rowbase + r * 66) * CSL + w * 8, dst + G * 8);
            }
        }
    };
    auto regA = [&](int ch) {
        // lane l reads granule base+l of each (gate,tap) block: fully coalesced 1KB/wave
        const unsigned short* s = A2 + (size_t)(ch * 4 + hg) * ASLAB_HW + lane * 8;
        #pragma unroll
        for (int i = 0; i < 27; ++i)
            a[i] = *(const bf16x8*)(s + (size_t)((i / 9) * 36 + (i % 9) * 4) * 128);
    };

    // B-read base: padded row 2w, col px, k-slice kl
    const int rb = (wave * 2 * PC + px) * CSL + kl * 8;

    // Compute one 32-channel chunk; while using a[], prefetch nextA's fragments
    // into the just-consumed slots (zero extra registers, hides L2 latency).
    auto compute = [&](const unsigned short* tb, bool isX, const unsigned short* nextA) {
        bf16x8 P[4][3];   // rows 2w..2w+3 x col shifts 0..2 (12 reads, dedup of 18)
        #pragma unroll
        for (int r = 0; r < 4; ++r)
            #pragma unroll
            for (int s = 0; s < 3; ++s)
                P[r][s] = *(const bf16x8*)(tb + rb + (r * PC + s) * CSL);
        #pragma unroll
        for (int dy = 0; dy < 3; ++dy) {
            #pragma unroll
            for (int dx = 0; dx < 3; ++dx) {
                const int tap = dy * 3 + dx;
                bf16x8 b0 = P[dy][dx], b1 = P[dy + 1][dx];
                bf16x8 ar = a[tap], az = a[9 + tap], an = a[18 + tap];
                if (nextA) {   // pipelined reload of this tap's 3 fragments
                    a[tap]      = *(const bf16x8*)(nextA + (size_t)(0 * 36 + tap * 4) * 128);
                    a[9 + tap]  = *(const bf16x8*)(nextA + (size_t)(1 * 36 + tap * 4) * 128);
                    a[18 + tap] = *(const bf16x8*)(nextA + (size_t)(2 * 36 + tap * 4) * 128);
                }
                accR[0] = __builtin_amdgcn_mfma_f32_16x16x32_bf16(ar, b0, accR[0], 0, 0, 0);
                accR[1] = __builtin_amdgcn_mfma_f32_16x16x32_bf16(ar, b1, accR[1], 0, 0, 0);
                accZ[0] = __builtin_amdgcn_mfma_f32_16x16x32_bf16(az, b0, accZ[0], 0, 0, 0);
                accZ[1] = __builtin_amdgcn_mfma_f32_16x16x32_bf16(az, b1, accZ[1], 0, 0, 0);
                if (isX) {
                    accNX[0] = __builtin_amdgcn_mfma_f32_16x16x32_bf16(an, b0, accNX[0], 0, 0, 0);
                    accNX[1] = __builtin_amdgcn_mfma_f32_16x16x32_bf16(an, b1, accNX[1], 0, 0, 0);
                } else {
                    accNH[0] = __builtin_amdgcn_mfma_f32_16x16x32_bf16(an, b0, accNH[0], 0, 0, 0);
                    accNH[1] = __builtin_amdgcn_mfma_f32_16x16x32_bf16(an, b1, accNH[1], 0, 0, 0);
                }
            }
        }
    };

    // ---- schedule: all DMA staging up front, ONE barrier ----
    stage_tin(xs, t0s);
    if (t > 0) {
        stage_tin(hTrd + (size_t)(b * 2 + 0) * PIMG_HW, t1s);
        stage_tin(hTrd + (size_t)(b * 2 + 1) * PIMG_HW, t2s);
    }
    regA(0);
    __syncthreads();                      // drains vmcnt: all tin + A(0) ready

    const unsigned short* A1p = (t > 0)
        ? A2 + (size_t)(1 * 4 + hg) * ASLAB_HW + lane * 8 : nullptr;
    const unsigned short* A2p = (t > 0)
        ? A2 + (size_t)(2 * 4 + hg) * ASLAB_HW + lane * 8 : nullptr;

    compute(t0s, true, A1p);
    if (t > 0) {
        compute(t1s, false, A2p);
        compute(t2s, false, nullptr);
    }

    // ---- epilogue: gates + state update; h_prev (bf16) from retained LDS ----
    float* outp = out + ((size_t)(b * T_ + t)) * HID * HW;
    const int c0   = hg * 16 + kl * 4;
    const int slot = c0 & 31;
    const unsigned short* hbuf = (hg < 2) ? t1s : t2s;
    #pragma unroll
    for (int g = 0; g < 2; ++g) {
        int gy = gy0 + wave * 2 + g;
        int gx = gx0 + px;
        float hvf[4] = {0.f, 0.f, 0.f, 0.f};
        if (t > 0) {
            const unsigned short* hp =
                hbuf + ((wave * 2 + g + 1) * PC + (px + 1)) * CSL + slot;
            #pragma unroll
            for (int q = 0; q < 4; ++q) hvf[q] = bf2f(hp[q]);
        }
        unsigned short hvals[4];
        #pragma unroll
        for (int q = 0; q < 4; ++q) {
            int c = c0 + q;
            float sr = __builtin_amdgcn_rcpf(1.f + __expf(-accR[g][q]));
            float sz = __builtin_amdgcn_rcpf(1.f + __expf(-accZ[g][q]));
            float ag = accNX[g][q] + sr * accNH[g][q];
            float nn = 2.f * __builtin_amdgcn_rcpf(1.f + __expf(-2.f * ag)) - 1.f;
            float hn = nn + sz * (hvf[q] - nn);
            outp[(size_t)c * HW + gy * WW + gx] = hn;
            hvals[q] = f2bf(hn);
        }
        unsigned short* hd = hTwr + (size_t)(b * 2 + (c0 >> 5)) * PIMG_HW
                           + (size_t)((gy + 1) * 66 + (gx + 1)) * CSL + slot;
        *(uint2*)hd = *(const uint2*)hvals;
    }
}

// ================= round-4 fallback (known-pass, tiny ws) =================
constexpr int F_AROWB = 640;
constexpr int R4_ASLAB = 48 * 9 * KCH;
constexpr int R4_AVEC  = R4_ASLAB / 8;
constexpr int R4_ATOT  = 12 * R4_ASLAB;
__global__ void wconv_r4(const float* __restrict__ Wi, const float* __restrict__ Wh,
                         unsigned short* __restrict__ A2) {
    int idx = blockIdx.x * 256 + threadIdx.x;
    if (idx >= R4_ATOT) return;
    int ic = idx & 31; int r1 = idx >> 5;
    int tap = r1 % 9; int r2 = r1 / 9;
    int m = r2 & 15; int r3 = r2 >> 4;
    int gt = r3 % 3; int r4 = r3 / 3;
    int hg = r4 & 3; int ch = r4 >> 2;
    int o = gt * 64 + hg * 16 + m;
    float w = (ch == 0) ? Wi[(o * CIN + ic) * 9 + tap]
                        : Wh[(o * HID + (ch - 1) * 32 + ic) * 9 + tap];
    A2[idx] = f2bf(w);
}
__global__ __launch_bounds__(256, 2) void convgru_r4(
    const float* __restrict__ x, const unsigned short* __restrict__ A2,
    const float* hall, float* out, int t)
{
    __shared__ __align__(16) unsigned short tin[PR * PC * 40];
    __shared__ __align__(16) unsigned short Alr[48 * (F_AROWB / 2)];
    const int tid = threadIdx.x;
    const int lane = tid & 63, wave = tid >> 6;
    const int px = lane & 15, kl = lane >> 4;
    const int ty = blockIdx.x >> 2, tx = blockIdx.x & 3;
    const int hg = blockIdx.y, b = blockIdx.z;
    const int gy0 = ty * TR, gx0 = tx * TC;
    const int nch = (t > 0) ? 3 : 1;
    const float* hb = (t > 0) ? (hall + ((size_t)(b * T_ + t - 1)) * HID * HW) : nullptr;
    const float* xb = x + ((size_t)(b * T_ + t)) * CIN * HW;
    f32x4 accR[2] = {}, accZ[2] = {}, accNX[2] = {}, accNH[2] = {};
    float ireg[23]; bf16x8 areg[7];
    auto load_in = [&](int ch) {
        const float* src = (ch == 0) ? xb : (hb + (size_t)(ch - 1) * KCH * HW);
        #pragma unroll
        for (int j = 0; j < 23; ++j) {
            int e = tid + j * 256; float v = 0.f;
            if (e < PR * PC * KCH) {
                int ic = e / (PR * PC); int rem = e - ic * (PR * PC);
                int r = rem / PC, c = rem - r * PC;
                int gy = gy0 + r - 1, gx = gx0 + c - 1;
                if ((unsigned)gy < (unsigned)HH && (unsigned)gx < (unsigned)WW)
                    v = src[ic * HW + gy * WW + gx];
            }
            ireg[j] = v;
        }
    };
    auto load_Ar = [&](int ch) {
        const unsigned short* s = A2 + (size_t)(ch * 4 + hg) * R4_ASLAB;
        #pragma unroll
        for (int j = 0; j < 7; ++j) { int v = tid + j * 256; if (v < R4_AVEC) areg[j] = *(const bf16x8*)(s + v * 8); }
    };
    auto write_in = [&]() {
        #pragma unroll
        for (int j = 0; j < 23; ++j) {
            int e = tid + j * 256;
            if (e < PR * PC * KCH) {
                int ic = e / (PR * PC); int rem = e - ic * (PR * PC);
                int r = rem / PC, c = rem - r * PC;
                tin[(r * PC + c) * 40 + ic] = f2bf(ireg[j]);
            }
        }
    };
    auto write_Ar = [&]() {
        #pragma unroll
        for (int j = 0; j < 7; ++j) {
            int v = tid + j * 256;
            if (v < R4_AVEC) {
                int row = v / 36; int kb = (v - row * 36) * 16;
                char* dst = (char*)Alr + row * F_AROWB + (kb ^ ((row & 7) << 4));
                *(bf16x8*)dst = areg[j];
            }
        }
    };
    const int rb0 = ((wave * 2 + 0) * PC + px) * 40 + kl * 8;
    const int rb1 = rb0 + PC * 40;
    const int swA = (px & 7) << 4;
    auto compute = [&](bool isX) {
        #pragma unroll
        for (int tap = 0; tap < 9; ++tap) {
            const int dy = tap / 3, dx = tap - 3 * dy;
            const int toff = (dy * PC + dx) * 40;
            bf16x8 b0 = *(const bf16x8*)(tin + rb0 + toff);
            bf16x8 b1 = *(const bf16x8*)(tin + rb1 + toff);
            const char* ab = (const char*)Alr + px * F_AROWB + ((tap * 64 + kl * 16) ^ swA);
            bf16x8 ar = *(const bf16x8*)(ab);
            bf16x8 az = *(const bf16x8*)(ab + 16 * F_AROWB);
            bf16x8 an = *(const bf16x8*)(ab + 32 * F_AROWB);
            accR[0] = __builtin_amdgcn_mfma_f32_16x16x32_bf16(ar, b0, accR[0], 0, 0, 0);
            accR[1] = __builtin_amdgcn_mfma_f32_16x16x32_bf16(ar, b1, accR[1], 0, 0, 0);
            accZ[0] = __builtin_amdgcn_mfma_f32_16x16x32_bf16(az, b0, accZ[0], 0, 0, 0);
            accZ[1] = __builtin_amdgcn_mfma_f32_16x16x32_bf16(az, b1, accZ[1], 0, 0, 0);
            if (isX) {
                accNX[0] = __builtin_amdgcn_mfma_f32_16x16x32_bf16(an, b0, accNX[0], 0, 0, 0);
                accNX[1] = __builtin_amdgcn_mfma_f32_16x16x32_bf16(an, b1, accNX[1], 0, 0, 0);
            } else {
                accNH[0] = __builtin_amdgcn_mfma_f32_16x16x32_bf16(an, b0, accNH[0], 0, 0, 0);
                accNH[1] = __builtin_amdgcn_mfma_f32_16x16x32_bf16(an, b1, accNH[1], 0, 0, 0);
            }
        }
    };
    load_in(0); load_Ar(0); write_in(); write_Ar();
    __syncthreads();
    for (int ch = 0; ch < nch; ++ch) {
        if (ch + 1 < nch) { load_in(ch + 1); load_Ar(ch + 1); }
        compute(ch == 0);
        __syncthreads();
        if (ch + 1 < nch) { write_in(); write_Ar(); __syncthreads(); }
    }
    float* outp = out + ((size_t)(b * T_ + t)) * HID * HW;
    #pragma unroll
    for (int g = 0; g < 2; ++g) {
        int gy = gy0 + wave * 2 + g; int gx = gx0 + px;
        #pragma unroll
        for (int q = 0; q < 4; ++q) {
            int c = hg * 16 + kl * 4 + q;
            float sr = 1.f / (1.f + expf(-accR[g][q]));
            float sz = 1.f / (1.f + expf(-accZ[g][q]));
            float nn = tanhf(accNX[g][q] + sr * accNH[g][q]);
            float hv = hb ? hb[(size_t)c * HW + gy * WW + gx] : 0.f;
            outp[(size_t)c * HW + gy * WW + gx] = (1.f - sz) * nn + sz * hv;
        }
    }
}

extern "C" void kernel_launch(void* const* d_in, const int* in_sizes, int n_in,
                              void* d_out, int out_size, void* d_ws, size_t ws_size,
                              hipStream_t stream) {
    const float* x  = (const float*)d_in[0];
    const float* Wi = (const float*)d_in[1];
    const float* Wh = (const float*)d_in[2];
    float* out = (float*)d_out;

    if (ws_size >= WS_NEED_BYTES) {
        unsigned short* A2  = (unsigned short*)d_ws;
        unsigned short* xT  = A2 + XT_OFF;
        unsigned short* hT0 = A2 + HT_OFF;
        unsigned short* hT1 = hT0 + HTBUF_HW;

        prep<<<PB_TOTAL, 256, 0, stream>>>(x, Wi, Wh, A2, xT, hT0);
        for (int t = 0; t < T_; ++t) {
            unsigned short* rd = (t & 1) ? hT1 : hT0;
            unsigned short* wr = (t & 1) ? hT0 : hT1;
            convgru_mfma<<<dim3(32, 4, 4), 256, 0, stream>>>(xT, A2, rd, wr, out, t);
        }
    } else {
        unsigned short* A2 = (unsigned short*)d_ws;
        wconv_r4<<<(R4_ATOT + 255) / 256, 256, 0, stream>>>(Wi, Wh, A2);
        for (int t = 0; t < T_; ++t)
            convgru_r4<<<dim3(32, 4, 4), 256, 0, stream>>>(x, A2, out, out, t);
    }
}